// Round 1
// baseline (520.041 us; speedup 1.0000x reference)
//
#include <hip/hip_runtime.h>

// FeatLUT: out[f] = quantize( mean_p( msb[idx_m(p)][f] + lsb[idx_l(p)][f] ) )
// idx = 16*(289*c0 + 17*c1 + c2)  -> only 17^3 = 4913 distinct rows used.
// Strategy: LDS histogram of the 4913 small indices per block, then per-block
// dot product against compacted tables, integer-exact global accumulation.

#define NBINS 4913            // 17^3
#define NPIX  (2048 * 2048)   // 4194304
#define G4    (NPIX / 4)      // 1048576 float4 groups per channel plane
#define NFEAT 20

// ---------------------------------------------------------------------------
// Kernel 0: compact the used LUT rows (row 16*j, j in [0,4913)) into dense
// 20-byte rows stored as 5 dwords each, and zero the final accumulator.
// Handles BOTH possible harness layouts for the int8 tables:
//   (a) raw int8 bytes, (b) widened to int32 (one int per int8 element).
// Detection: in layout (b) every int is in [-32, 32); in layout (a) a dword
// packs 4 random bytes and essentially never stays in that range 64x in a row.
// ---------------------------------------------------------------------------
__global__ __launch_bounds__(256) void compact_k(const int* __restrict__ msb,
                                                 const int* __restrict__ lsb,
                                                 int* __restrict__ cm,
                                                 int* __restrict__ cl,
                                                 int* __restrict__ gacc) {
    if (blockIdx.x == 0 && threadIdx.x < NFEAT) gacc[threadIdx.x] = 0;

    // layout detection (uniform across all threads; cached reads)
    int ok = 1;
    for (int i = 0; i < 64; ++i) {
        int v = msb[i];
        ok &= (v >= -32 && v < 32);
    }
    const bool is_int32 = (ok != 0);

    const int total = NBINS * 5;  // dwords per compact table
    int t = blockIdx.x * 256 + threadIdx.x;
    const int stride = gridDim.x * 256;
    for (; t < total; t += stride) {
        int j = t / 5;
        int k = t - j * 5;
        int wm, wl;
        if (is_int32) {
            // source: int per element; row 16j starts at element 16j*20 = 320j
            const int* rm = msb + j * 320 + k * 4;
            const int* rl = lsb + j * 320 + k * 4;
            unsigned um = (unsigned)(rm[0] & 0xff) | ((unsigned)(rm[1] & 0xff) << 8) |
                          ((unsigned)(rm[2] & 0xff) << 16) | ((unsigned)(rm[3] & 0xff) << 24);
            unsigned ul = (unsigned)(rl[0] & 0xff) | ((unsigned)(rl[1] & 0xff) << 8) |
                          ((unsigned)(rl[2] & 0xff) << 16) | ((unsigned)(rl[3] & 0xff) << 24);
            wm = (int)um;
            wl = (int)ul;
        } else {
            // source: raw int8; row 16j at byte 320j -> dword 80j, 5 dwords/row
            wm = msb[j * 80 + k];
            wl = lsb[j * 80 + k];
        }
        cm[t] = wm;
        cl[t] = wl;
    }
}

// ---------------------------------------------------------------------------
// Kernel 1: main. 512 blocks x 256 threads.
//  - LDS histograms (2 x 4913 ints = 39.3 KB)
//  - float4 streaming of x_in / x_s (exactly 8 grid-stride iters, no tail)
//  - per-block dot against compact tables, wave shuffle reduce, 20 atomics
// ---------------------------------------------------------------------------
__global__ __launch_bounds__(256) void feat_main(const float* __restrict__ xin,
                                                 const float* __restrict__ xs,
                                                 const int* __restrict__ cm,
                                                 const int* __restrict__ cl,
                                                 int* __restrict__ gacc) {
    __shared__ int hist[2 * NBINS];  // [0,NBINS): msb, [NBINS,2*NBINS): lsb
    for (int i = threadIdx.x; i < 2 * NBINS; i += 256) hist[i] = 0;
    __syncthreads();

    const float4* a = (const float4*)xin;
    const float4* b = (const float4*)xs;
    const int nt = gridDim.x * 256;
    for (int g = blockIdx.x * 256 + threadIdx.x; g < G4; g += nt) {
        float4 a0 = a[g], a1 = a[g + G4], a2 = a[g + 2 * G4];
        float4 b0 = b[g], b1 = b[g + G4], b2 = b[g + 2 * G4];

        int m0 = (int)fmaf(a0.x, 289.0f, fmaf(a1.x, 17.0f, a2.x));
        int m1 = (int)fmaf(a0.y, 289.0f, fmaf(a1.y, 17.0f, a2.y));
        int m2 = (int)fmaf(a0.z, 289.0f, fmaf(a1.z, 17.0f, a2.z));
        int m3 = (int)fmaf(a0.w, 289.0f, fmaf(a1.w, 17.0f, a2.w));
        int s0 = (int)fmaf(b0.x, 289.0f, fmaf(b1.x, 17.0f, b2.x));
        int s1 = (int)fmaf(b0.y, 289.0f, fmaf(b1.y, 17.0f, b2.y));
        int s2 = (int)fmaf(b0.z, 289.0f, fmaf(b1.z, 17.0f, b2.z));
        int s3 = (int)fmaf(b0.w, 289.0f, fmaf(b1.w, 17.0f, b2.w));

        atomicAdd(&hist[m0], 1);
        atomicAdd(&hist[m1], 1);
        atomicAdd(&hist[m2], 1);
        atomicAdd(&hist[m3], 1);
        atomicAdd(&hist[NBINS + s0], 1);
        atomicAdd(&hist[NBINS + s1], 1);
        atomicAdd(&hist[NBINS + s2], 1);
        atomicAdd(&hist[NBINS + s3], 1);
    }
    __syncthreads();

    // per-block dot product: acc[f] += hist_m[j]*msb_row[j][f] + hist_l[j]*lsb_row[j][f]
    int acc[NFEAT];
#pragma unroll
    for (int f = 0; f < NFEAT; ++f) acc[f] = 0;

    for (int j = threadIdx.x; j < NBINS; j += 256) {
        int hm = hist[j];
        int hl = hist[NBINS + j];
        if (hm) {
            const int* r = cm + j * 5;
#pragma unroll
            for (int k = 0; k < 5; ++k) {
                int w = r[k];
                acc[4 * k + 0] += hm * ((w << 24) >> 24);
                acc[4 * k + 1] += hm * ((w << 16) >> 24);
                acc[4 * k + 2] += hm * ((w << 8) >> 24);
                acc[4 * k + 3] += hm * (w >> 24);
            }
        }
        if (hl) {
            const int* r = cl + j * 5;
#pragma unroll
            for (int k = 0; k < 5; ++k) {
                int w = r[k];
                acc[4 * k + 0] += hl * ((w << 24) >> 24);
                acc[4 * k + 1] += hl * ((w << 16) >> 24);
                acc[4 * k + 2] += hl * ((w << 8) >> 24);
                acc[4 * k + 3] += hl * (w >> 24);
            }
        }
    }

    // wave butterfly reduce, then one atomic per wave per feature
    const int lane = threadIdx.x & 63;
#pragma unroll
    for (int f = 0; f < NFEAT; ++f) {
        int v = acc[f];
#pragma unroll
        for (int o = 32; o > 0; o >>= 1) v += __shfl_xor(v, o, 64);
        if (lane == 0) atomicAdd(&gacc[f], v);
    }
}

// ---------------------------------------------------------------------------
// Kernel 2: finalize. mean*4 = S / 2^20 exactly; RNE rint == jnp.round.
// ---------------------------------------------------------------------------
__global__ void finalize_k(const int* __restrict__ gacc, float* __restrict__ out) {
    int f = threadIdx.x;
    if (f < NFEAT) {
        double m4 = (double)gacc[f] * (1.0 / 1048576.0);
        double r = rint(m4);
        float v = (float)(r * 0.25);
        v = fminf(fmaxf(v, -32.0f), 31.75f);
        out[f] = v;
    }
}

extern "C" void kernel_launch(void* const* d_in, const int* in_sizes, int n_in,
                              void* d_out, int out_size, void* d_ws, size_t ws_size,
                              hipStream_t stream) {
    const float* xin = (const float*)d_in[0];
    const float* xs = (const float*)d_in[1];
    const int* msb = (const int*)d_in[2];
    const int* lsb = (const int*)d_in[3];
    float* out = (float*)d_out;

    // workspace layout: [0,80): gacc (20 ints); compact tables after 128B
    int* gacc = (int*)d_ws;
    int* cm = (int*)((char*)d_ws + 128);
    int* cl = (int*)((char*)d_ws + 128 + 98304);  // 24565 dwords -> pad to 96 KiB

    compact_k<<<96, 256, 0, stream>>>(msb, lsb, cm, cl, gacc);
    feat_main<<<512, 256, 0, stream>>>(xin, xs, cm, cl, gacc);
    finalize_k<<<1, 64, 0, stream>>>(gacc, out);
}

// Round 2
// 158.183 us; speedup vs baseline: 3.2876x; 3.2876x over previous
//
#include <hip/hip_runtime.h>

// FeatLUT: out[f] = quantize( mean_p( msb[idx_m(p)][f] + lsb[idx_l(p)][f] ) )
// idx = 16*(289*c0 + 17*c1 + c2)  -> only 17^3 = 4913 distinct rows used.
// Strategy: per-block LDS histogram of the 4913 small indices, per-block dot
// against compacted tables -> NON-ATOMIC per-block partials, tree-reduce.
// (R1 lesson: 40960 same-cacheline global atomics serialized = 417us.)

#define NBINS 4913            // 17^3
#define NPIX  (2048 * 2048)   // 4194304
#define G4    (NPIX / 4)      // 1048576 float4 groups per channel plane
#define NFEAT 20
#define MAIN_BLOCKS 1024      // 4 blocks/CU, LDS 4*39424=157696 <= 163840

// ---------------------------------------------------------------------------
// Kernel 0: compact the used LUT rows (row 16*j, j in [0,4913)) into dense
// 20-byte rows stored as 5 dwords each. Handles both harness layouts for the
// int8 tables: (a) raw int8 bytes, (b) widened to int32. Detection: random
// packed bytes essentially never stay in [-32,32) 64x in a row.
// ---------------------------------------------------------------------------
__global__ __launch_bounds__(256) void compact_k(const int* __restrict__ msb,
                                                 const int* __restrict__ lsb,
                                                 int* __restrict__ cm,
                                                 int* __restrict__ cl) {
    int ok = 1;
    for (int i = 0; i < 64; ++i) {
        int v = msb[i];
        ok &= (v >= -32 && v < 32);
    }
    const bool is_int32 = (ok != 0);

    const int total = NBINS * 5;  // dwords per compact table
    int t = blockIdx.x * 256 + threadIdx.x;
    const int stride = gridDim.x * 256;
    for (; t < total; t += stride) {
        int j = t / 5;
        int k = t - j * 5;
        int wm, wl;
        if (is_int32) {
            // source: int per element; row 16j starts at element 16j*20 = 320j
            const int* rm = msb + j * 320 + k * 4;
            const int* rl = lsb + j * 320 + k * 4;
            unsigned um = (unsigned)(rm[0] & 0xff) | ((unsigned)(rm[1] & 0xff) << 8) |
                          ((unsigned)(rm[2] & 0xff) << 16) | ((unsigned)(rm[3] & 0xff) << 24);
            unsigned ul = (unsigned)(rl[0] & 0xff) | ((unsigned)(rl[1] & 0xff) << 8) |
                          ((unsigned)(rl[2] & 0xff) << 16) | ((unsigned)(rl[3] & 0xff) << 24);
            wm = (int)um;
            wl = (int)ul;
        } else {
            // source: raw int8; row 16j at byte 320j -> dword 80j, 5 dwords/row
            wm = msb[j * 80 + k];
            wl = lsb[j * 80 + k];
        }
        cm[t] = wm;
        cl[t] = wl;
    }
}

// ---------------------------------------------------------------------------
// Kernel 1: main. MAIN_BLOCKS x 256 threads.
//  - LDS histograms (2 x 4913 ints = 39.3 KB)
//  - float4 streaming of x_in / x_s (exactly 4 grid-stride iters, no tail)
//  - per-block dot against compact tables, wave shuffle reduce, LDS combine,
//    one NON-ATOMIC 20-int partial row per block.
// ---------------------------------------------------------------------------
__global__ __launch_bounds__(256) void feat_main(const float* __restrict__ xin,
                                                 const float* __restrict__ xs,
                                                 const int* __restrict__ cm,
                                                 const int* __restrict__ cl,
                                                 int* __restrict__ partial) {
    __shared__ int hist[2 * NBINS];  // [0,NBINS): msb, [NBINS,2*NBINS): lsb
    __shared__ int wsum[4][NFEAT];
    for (int i = threadIdx.x; i < 2 * NBINS; i += 256) hist[i] = 0;
    __syncthreads();

    const float4* a = (const float4*)xin;
    const float4* b = (const float4*)xs;
    const int nt = MAIN_BLOCKS * 256;
    for (int g = blockIdx.x * 256 + threadIdx.x; g < G4; g += nt) {
        float4 a0 = a[g], a1 = a[g + G4], a2 = a[g + 2 * G4];
        float4 b0 = b[g], b1 = b[g + G4], b2 = b[g + 2 * G4];

        int m0 = (int)fmaf(a0.x, 289.0f, fmaf(a1.x, 17.0f, a2.x));
        int m1 = (int)fmaf(a0.y, 289.0f, fmaf(a1.y, 17.0f, a2.y));
        int m2 = (int)fmaf(a0.z, 289.0f, fmaf(a1.z, 17.0f, a2.z));
        int m3 = (int)fmaf(a0.w, 289.0f, fmaf(a1.w, 17.0f, a2.w));
        int s0 = (int)fmaf(b0.x, 289.0f, fmaf(b1.x, 17.0f, b2.x));
        int s1 = (int)fmaf(b0.y, 289.0f, fmaf(b1.y, 17.0f, b2.y));
        int s2 = (int)fmaf(b0.z, 289.0f, fmaf(b1.z, 17.0f, b2.z));
        int s3 = (int)fmaf(b0.w, 289.0f, fmaf(b1.w, 17.0f, b2.w));

        atomicAdd(&hist[m0], 1);
        atomicAdd(&hist[m1], 1);
        atomicAdd(&hist[m2], 1);
        atomicAdd(&hist[m3], 1);
        atomicAdd(&hist[NBINS + s0], 1);
        atomicAdd(&hist[NBINS + s1], 1);
        atomicAdd(&hist[NBINS + s2], 1);
        atomicAdd(&hist[NBINS + s3], 1);
    }
    __syncthreads();

    // per-block dot product: acc[f] += hist_m[j]*msb_row[j][f] + hist_l[j]*lsb_row[j][f]
    int acc[NFEAT];
#pragma unroll
    for (int f = 0; f < NFEAT; ++f) acc[f] = 0;

    for (int j = threadIdx.x; j < NBINS; j += 256) {
        int hm = hist[j];
        int hl = hist[NBINS + j];
        if (hm) {
            const int* r = cm + j * 5;
#pragma unroll
            for (int k = 0; k < 5; ++k) {
                int w = r[k];
                acc[4 * k + 0] += hm * ((w << 24) >> 24);
                acc[4 * k + 1] += hm * ((w << 16) >> 24);
                acc[4 * k + 2] += hm * ((w << 8) >> 24);
                acc[4 * k + 3] += hm * (w >> 24);
            }
        }
        if (hl) {
            const int* r = cl + j * 5;
#pragma unroll
            for (int k = 0; k < 5; ++k) {
                int w = r[k];
                acc[4 * k + 0] += hl * ((w << 24) >> 24);
                acc[4 * k + 1] += hl * ((w << 16) >> 24);
                acc[4 * k + 2] += hl * ((w << 8) >> 24);
                acc[4 * k + 3] += hl * (w >> 24);
            }
        }
    }

    // wave butterfly reduce -> LDS per-wave row -> thread f sums 4 rows ->
    // one non-atomic global partial row per block.
    const int lane = threadIdx.x & 63;
    const int wv = threadIdx.x >> 6;
#pragma unroll
    for (int f = 0; f < NFEAT; ++f) {
        int v = acc[f];
#pragma unroll
        for (int o = 32; o > 0; o >>= 1) v += __shfl_xor(v, o, 64);
        if (lane == 0) wsum[wv][f] = v;
    }
    __syncthreads();
    if (threadIdx.x < NFEAT) {
        int f = threadIdx.x;
        partial[blockIdx.x * NFEAT + f] = wsum[0][f] + wsum[1][f] + wsum[2][f] + wsum[3][f];
    }
}

// ---------------------------------------------------------------------------
// Kernel 2: finalize. Block f (of 20) sums partial[b][f] over 1024 blocks,
// then quantizes exactly: mean*4 = S / 2^20; RNE rint == jnp.round.
// ---------------------------------------------------------------------------
__global__ __launch_bounds__(64) void finalize_k(const int* __restrict__ partial,
                                                 float* __restrict__ out) {
    const int f = blockIdx.x;
    const int lane = threadIdx.x;
    int s = 0;
    for (int b = lane; b < MAIN_BLOCKS; b += 64) s += partial[b * NFEAT + f];
#pragma unroll
    for (int o = 32; o > 0; o >>= 1) s += __shfl_xor(s, o, 64);
    if (lane == 0) {
        double m4 = (double)s * (1.0 / 1048576.0);
        double r = rint(m4);
        float v = (float)(r * 0.25);
        v = fminf(fmaxf(v, -32.0f), 31.75f);
        out[f] = v;
    }
}

extern "C" void kernel_launch(void* const* d_in, const int* in_sizes, int n_in,
                              void* d_out, int out_size, void* d_ws, size_t ws_size,
                              hipStream_t stream) {
    const float* xin = (const float*)d_in[0];
    const float* xs = (const float*)d_in[1];
    const int* msb = (const int*)d_in[2];
    const int* lsb = (const int*)d_in[3];
    float* out = (float*)d_out;

    // workspace layout: compact tables (2 x 96 KiB), then per-block partials
    int* cm = (int*)d_ws;
    int* cl = (int*)((char*)d_ws + 98304);
    int* partial = (int*)((char*)d_ws + 2 * 98304);  // 1024*20*4 = 80 KiB

    compact_k<<<96, 256, 0, stream>>>(msb, lsb, cm, cl);
    feat_main<<<MAIN_BLOCKS, 256, 0, stream>>>(xin, xs, cm, cl, partial);
    finalize_k<<<NFEAT, 64, 0, stream>>>(partial, out);
}